// Round 17
// baseline (104.024 us; speedup 1.0000x reference)
//
#include <hip/hip_runtime.h>
#include <cfloat>
#include <cstdint>

#define THRESH 1.25e-4f

typedef __attribute__((ext_vector_type(8))) _Float16 half8;        // 8 fp16 (4 VGPR) MFMA A/B frag
typedef __attribute__((ext_vector_type(8))) unsigned short upk8;   // packing vector
typedef __attribute__((ext_vector_type(4))) float facc4;           // MFMA C/D frag

__device__ __forceinline__ unsigned short f2h(float x) {
  _Float16 h = (_Float16)x;     // RNE
  return __builtin_bit_cast(unsigned short, h);
}

// ws layout (float offsets):
// 0      Csq[1024]
// 1024   A[32768]           (||z||^2, written by phase1)
// 66560  flagCount (int, +16 pad)
// 66576  flagList[32768] (int)
// 99344  ehT[262144] ushort (fp16 codebook, k-major: [kg=32][code=1024][8])

__global__ __launch_bounds__(256) void precompute_kernel(
    const float* __restrict__ emb, float* __restrict__ Csq,
    unsigned short* __restrict__ ehT, int* __restrict__ flagCount) {
  int blk = blockIdx.x, t = threadIdx.x;
  if (blk < 4) {
    int k = blk * 256 + t;
    const float4* e4 = (const float4*)(emb + ((size_t)k << 8));
    double acc = 0.0;
    for (int d4 = 0; d4 < 64; ++d4) {
      float4 e = e4[d4];
      acc += (double)(e.x * e.x) + (double)(e.y * e.y) +
             (double)(e.z * e.z) + (double)(e.w * e.w);
    }
    Csq[k] = (float)acc;
    if (blk == 0 && t == 0) *flagCount = 0;
  } else {
    // k-major fp16 codebook: ehT[(kg*1024 + code)*8 + j] = fp16(emb[code][kg*8+j])
    int linear = (blk - 4) * 256 + t;           // 0..32767
    int code = linear & 1023, kg = linear >> 10;
    const float* ep = emb + ((size_t)code << 8) + (kg << 3);
    float4 e0 = *(const float4*)ep;
    float4 e1 = *(const float4*)(ep + 4);
    upk8 pk;
    pk[0] = f2h(e0.x); pk[1] = f2h(e0.y); pk[2] = f2h(e0.z); pk[3] = f2h(e0.w);
    pk[4] = f2h(e1.x); pk[5] = f2h(e1.y); pk[6] = f2h(e1.z); pk[7] = f2h(e1.w);
    *(upk8*)(ehT + ((size_t)linear << 3)) = pk;
  }
}

// Stage half-slab h (codes h*128 .. h*128+127, all 32 kg-octs) into a 64KB buf.
// LDS layout: [kg=32][cl=128][8 fp16] linear; per wave 8 glds_dwordx4 (vmcnt +8).
__device__ __forceinline__ void stage_half(
    const unsigned short* __restrict__ ehT, char* buf, int h, int t) {
  int w6 = t & 0x1C0;                       // wave<<6
#pragma unroll
  for (int i = 0; i < 8; ++i) {
    int slot = (i << 9) + t;                // 0..4095 (16B units)
    int kg = slot >> 7, cl = slot & 127;
    const unsigned short* g = ehT + (((size_t)(kg << 10) + (h << 7) + cl) << 3);
    char* lp = buf + (((i << 9) + w6) << 4);    // wave-uniform
    __builtin_amdgcn_global_load_lds(
        (const __attribute__((address_space(1))) unsigned int*)g,
        (__attribute__((address_space(3))) unsigned int*)lp, 16, 0, 0);
  }
}

// Phase 1: fp16 MFMA GEMM-argmin (r11 core, best verified 46us) + FUSED GATHER.
// Block = 128 vectors x 1024 codes, 512 threads (8 waves), grid 256 (1 blk/CU).
// After the argmin merge, the block gathers emb[idx] rows through the (now
// dead) 135KB staging LDS and writes out0/out1/out2 directly -- the stores
// issue into phase1's abundant stall slots, deleting the serial gather kernel.
// Phase2 later patches the ~650 flagged vectors in place.
__global__ __launch_bounds__(512) __attribute__((amdgpu_waves_per_eu(2, 2)))
void phase1_kernel(
    const float* __restrict__ z, const unsigned short* __restrict__ ehT,
    const float* __restrict__ Csq, const float* __restrict__ emb,
    float* __restrict__ A, float* __restrict__ out,
    int* __restrict__ flagCount, int* __restrict__ flagList) {
  __shared__ char lds[135168] __attribute__((aligned(16)));  // bufA|bufB, then se[256][132]
  __shared__ float Cs[1024];
  __shared__ float mm1[2][4][32], mm2[2][4][32];
  __shared__ int mbi[2][4][32];
  __shared__ int fidx[128];
  char* bufA = lds;
  char* bufB = lds + 65536;

  int t = threadIdx.x;
  int n0 = blockIdx.x << 7;                 // 128 vectors per block
  int b = n0 >> 10, wh0 = n0 & 1023;
  int w = t >> 6, l = t & 63;
  int wv = w & 3, wn = w >> 2;
  int lx = l & 15, lg = l >> 4;

  stage_half(ehT, bufA, 0, t);              // halves 0,1 fly during A-phase
  stage_half(ehT, bufB, 1, t);
  ((float2*)Cs)[t] = ((const float2*)Csq)[t];

  // ---- A-fragments from global z (coalesced 64B clusters), norms for free
  half8 afr[2][8];
  double nacc[2] = {0.0, 0.0};
  const float* zb = z + (((size_t)(b * 256)) << 10) + wh0 + wv * 32 + lx;
#pragma unroll
  for (int mi = 0; mi < 2; ++mi) {
#pragma unroll
    for (int kk = 0; kk < 8; ++kk) {
      upk8 pk;
#pragma unroll
      for (int j = 0; j < 8; ++j) {
        int c = kk * 32 + lg * 8 + j;
        float x = zb[((size_t)c << 10) + mi * 16];
        nacc[mi] += (double)(x * x);
        pk[j] = f2h(-2.0f * x);
      }
      afr[mi][kk] = __builtin_bit_cast(half8, pk);
    }
  }
#pragma unroll
  for (int mi = 0; mi < 2; ++mi) {
    double s = nacc[mi];
    s += __shfl_xor(s, 16);
    s += __shfl_xor(s, 32);
    if (wn == 0 && lg == 0) A[n0 + wv * 32 + mi * 16 + lx] = (float)s;
  }
  __syncthreads();   // full drain: halves 0,1 + Cs ready, vmcnt ledger = 0

  float m1[8], m2[8];
  int bi[8];
#pragma unroll
  for (int s8 = 0; s8 < 8; ++s8) { m1[s8] = FLT_MAX; m2[s8] = FLT_MAX; bi[s8] = 0; }

#pragma unroll 1
  for (int h = 0; h < 8; ++h) {
    // ---- compute on resident half h: 32 vec x 64 codes x K=256 per wave
    const char* buf = (h & 1) ? bufB : bufA;
    facc4 acc[2][4];
#pragma unroll
    for (int mi = 0; mi < 2; ++mi)
#pragma unroll
      for (int nj = 0; nj < 4; ++nj) {
        facc4 zf = {0.0f, 0.0f, 0.0f, 0.0f};
        acc[mi][nj] = zf;
      }
#pragma unroll
    for (int kk = 0; kk < 8; ++kk) {
      // addr16 = (kk*4+lg)*128 + wn*64 + nj*16 + lx
      const char* base = buf + (((((kk << 2) + lg) << 7) + (wn << 6) + lx) << 4);
#pragma unroll
      for (int nj = 0; nj < 4; ++nj) {
        half8 bv = *(const half8*)(base + (nj << 8));
        acc[0][nj] = __builtin_amdgcn_mfma_f32_16x16x32_f16(afr[0][kk], bv, acc[0][nj], 0, 0, 0);
        acc[1][nj] = __builtin_amdgcn_mfma_f32_16x16x32_f16(afr[1][kk], bv, acc[1][nj], 0, 0, 0);
      }
    }
    // branchless min-update; C/D frag: col=lane&15 (code), row=lg*4+reg (vector)
    int cbase = (h << 7) + (wn << 6);
#pragma unroll
    for (int nj = 0; nj < 4; ++nj) {
      float csv = Cs[cbase + nj * 16 + lx];
      int code = cbase + nj * 16 + lx;
#pragma unroll
      for (int mi = 0; mi < 2; ++mi)
#pragma unroll
        for (int reg = 0; reg < 4; ++reg) {
          int s8 = mi * 4 + reg;
          float sv = acc[mi][nj][reg] + csv;
          float hi = fmaxf(sv, m1[s8]);
          bool lt = sv < m1[s8];
          m1[s8] = lt ? sv : m1[s8];
          bi[s8] = lt ? code : bi[s8];
          m2[s8] = fminf(m2[s8], hi);
        }
    }
    if (h < 7) {
      asm volatile("s_waitcnt lgkmcnt(0)" ::: "memory");
      __builtin_amdgcn_s_barrier();          // all waves done reading buf[h&1]
      if (h < 6) {
        stage_half(ehT, (h & 1) ? bufB : bufA, h + 2, t);
        asm volatile("s_waitcnt vmcnt(8)" ::: "memory");   // stage(h+1) retired
      } else {
        asm volatile("s_waitcnt vmcnt(0)" ::: "memory");   // last half: full drain
      }
      __builtin_amdgcn_s_barrier();          // buf[(h+1)&1] ready for all waves
    }
  }

  // ---- reduce 16 lanes sharing each vector, then merge the two code-half waves
#pragma unroll
  for (int s8 = 0; s8 < 8; ++s8) {
    float M1 = m1[s8], M2 = m2[s8];
    int BI = bi[s8];
    for (int off = 8; off > 0; off >>= 1) {
      float om1 = __shfl_xor(M1, off, 16);
      float om2 = __shfl_xor(M2, off, 16);
      int obi = __shfl_xor(BI, off, 16);
      float lo = fminf(M2, om2);
      bool take = (om1 < M1) || (om1 == M1 && obi < BI);
      float loser = take ? M1 : om1;
      M2 = fminf(lo, loser);
      if (take) { M1 = om1; BI = obi; }
    }
    if (lx == 0) {
      int row = ((s8 >> 2) << 4) + (lg << 2) + (s8 & 3);
      mm1[wn][wv][row] = M1; mm2[wn][wv][row] = M2; mbi[wn][wv][row] = BI;
    }
  }
  __syncthreads();   // also: all LDS reads of bufA/bufB complete block-wide
  if (wn == 0 && lx == 0) {
#pragma unroll
    for (int s8 = 0; s8 < 8; ++s8) {
      int row = ((s8 >> 2) << 4) + (lg << 2) + (s8 & 3);
      float a1v = mm1[0][wv][row], a2v = mm2[0][wv][row];
      int ab = mbi[0][wv][row];
      float b1v = mm1[1][wv][row], b2v = mm2[1][wv][row];
      int bb = mbi[1][wv][row];
      bool tb = (b1v < a1v) || (b1v == a1v && bb < ab);
      float M1 = tb ? b1v : a1v;
      int BI = tb ? bb : ab;
      float M2 = fminf(fminf(a2v, b2v), tb ? a1v : b1v);
      int rowi = wv * 32 + row;
      fidx[rowi] = BI;
      if (M2 - M1 < THRESH) {
        int pos = atomicAdd(flagCount, 1);
        flagList[pos] = n0 + rowi;
      }
    }
  }
  __syncthreads();   // fidx visible to all

  // ---- fused gather: out2 = idx; out0 = out1 = emb[idx] (provisional; phase2
  // patches flagged). se[256][132] fp32 aliases the dead staging LDS.
  float* out2 = out + 16777216;
  if (t < 128) out2[n0 + t] = (float)fidx[t];
  float* se = (float*)lds;
  {
    int v = t >> 3, d8 = t & 7;      // 64 vectors/pass, 8 thr/vector (128B runs)
#pragma unroll 1
    for (int pass = 0; pass < 2; ++pass) {
      int vv = pass * 64 + v;
      const float4* e4 = (const float4*)(emb + ((size_t)fidx[vv] << 8));
#pragma unroll
      for (int it = 0; it < 8; ++it) {
        int d4 = it * 8 + d8;
        float4 e = e4[d4];
        se[(d4 * 4 + 0) * 132 + vv] = e.x;
        se[(d4 * 4 + 1) * 132 + vv] = e.y;
        se[(d4 * 4 + 2) * 132 + vv] = e.z;
        se[(d4 * 4 + 3) * 132 + vv] = e.w;
      }
    }
  }
  __syncthreads();
  {
    float* out0 = out;
    float* out1 = out + 8388608;
    int slot = t & 31, crow = t >> 5;   // 32 f4-slots (128 wh) x 16 c-rows/iter
#pragma unroll 1
    for (int it = 0; it < 16; ++it) {
      int c = it * 16 + crow;
      float4 val = *(const float4*)&se[c * 132 + slot * 4];
      size_t o = (((size_t)(b * 256 + c)) << 10) + wh0 + slot * 4;
      *(float4*)(out0 + o) = val;
      *(float4*)(out1 + o) = val;
    }
  }
}

// Phase 2: fp32 reference-formula emulation for flagged vectors, then patch
// out0/out1/out2 in place (scattered 4B stores; ~650 vectors total).
// q_k = fp32((A - 2*dot32) + C_k), exact compare, first-index tie-break.
__global__ __launch_bounds__(256) void phase2_kernel(
    const float* __restrict__ z, const float* __restrict__ emb,
    const float* __restrict__ Csq, const float* __restrict__ A,
    float* __restrict__ out, const int* __restrict__ flagCount,
    const int* __restrict__ flagList) {
  __shared__ float zq[4][260];
  __shared__ float Anv[4];
  __shared__ int nn[4];
  __shared__ float sq[4][4];
  __shared__ int sk[4][4];
  __shared__ int skk[4];
  int t = threadIdx.x;
  int w = t >> 6, l = t & 63;
  int cnt = *flagCount;
  int nit = (cnt + 3) >> 2;
  for (int it = blockIdx.x; it < nit; it += gridDim.x) {
    __syncthreads();   // protect zq/nn/sq/skk reuse across grid-stride iterations
    int base = it << 2;
    int mcnt = min(4, cnt - base);
    if (t < 4) {
      if (t < mcnt) { int n = flagList[base + t]; nn[t] = n; Anv[t] = A[n]; }
      else nn[t] = -1;
    }
    __syncthreads();
#pragma unroll
    for (int v = 0; v < 4; ++v) {
      int n = nn[v];
      if (n >= 0) {
        int bb = n >> 10, wh = n & 1023;
        zq[v][t] = z[(((size_t)(bb * 256 + t)) << 10) + wh];
      }
    }
    __syncthreads();

    float dot[4][4];
#pragma unroll
    for (int r = 0; r < 4; ++r)
#pragma unroll
      for (int v = 0; v < 4; ++v) dot[r][v] = 0.0f;

    const float4* e0 = (const float4*)(emb + ((size_t)(t + 0) << 8));
    const float4* e1 = (const float4*)(emb + ((size_t)(t + 256) << 8));
    const float4* e2 = (const float4*)(emb + ((size_t)(t + 512) << 8));
    const float4* e3 = (const float4*)(emb + ((size_t)(t + 768) << 8));
#pragma unroll 8
    for (int d4 = 0; d4 < 64; ++d4) {
      float4 ea = e0[d4], eb = e1[d4], ec = e2[d4], ed = e3[d4];
#pragma unroll
      for (int v = 0; v < 4; ++v) {
        float4 zv = *(const float4*)&zq[v][d4 * 4];
        dot[0][v] += zv.x * ea.x + zv.y * ea.y + zv.z * ea.z + zv.w * ea.w;
        dot[1][v] += zv.x * eb.x + zv.y * eb.y + zv.z * eb.z + zv.w * eb.w;
        dot[2][v] += zv.x * ec.x + zv.y * ec.y + zv.z * ec.z + zv.w * ec.w;
        dot[3][v] += zv.x * ed.x + zv.y * ed.y + zv.z * ed.z + zv.w * ed.w;
      }
    }

    float bq[4];
    int bk[4];
#pragma unroll
    for (int v = 0; v < 4; ++v) { bq[v] = FLT_MAX; bk[v] = 0; }
#pragma unroll
    for (int r = 0; r < 4; ++r) {
      int k = t + (r << 8);
      float Ck = Csq[k];
#pragma unroll
      for (int v = 0; v < 4; ++v) {
        float qv = (Anv[v] - 2.0f * dot[r][v]) + Ck;
        if (qv < bq[v]) { bq[v] = qv; bk[v] = k; }   // within-thread k ascending
      }
    }

#pragma unroll
    for (int v = 0; v < 4; ++v) {
      float q = bq[v];
      int kk = bk[v];
      for (int off = 32; off > 0; off >>= 1) {
        float oq = __shfl_xor(q, off);
        int ok = __shfl_xor(kk, off);
        if (oq < q || (oq == q && ok < kk)) { q = oq; kk = ok; }
      }
      if (l == 0) { sq[v][w] = q; sk[v][w] = kk; }
    }
    __syncthreads();
    if (t < mcnt) {
      float q = sq[t][0];
      int kk = sk[t][0];
#pragma unroll
      for (int j = 1; j < 4; ++j) {
        float oq = sq[t][j];
        int ok = sk[t][j];
        if (oq < q || (oq == q && ok < kk)) { q = oq; kk = ok; }
      }
      skk[t] = kk;
    }
    __syncthreads();
    // patch outputs for this iteration's flagged vectors
    for (int v = 0; v < mcnt; ++v) {
      int n = nn[v];
      int kk2 = skk[v];
      int bb = n >> 10, wh = n & 1023;
      float val = emb[((size_t)kk2 << 8) + t];   // thread t = channel c
      size_t o = (((size_t)(bb * 256 + t)) << 10) + wh;
      out[o] = val;
      out[8388608 + o] = val;
      if (t == 0) out[16777216 + n] = (float)kk2;
    }
  }
}

extern "C" void kernel_launch(void* const* d_in, const int* in_sizes, int n_in,
                              void* d_out, int out_size, void* d_ws, size_t ws_size,
                              hipStream_t stream) {
  const float* z = (const float*)d_in[0];
  const float* emb = (const float*)d_in[1];
  float* ws = (float*)d_ws;
  float* Csq = ws;
  float* A = ws + 1024;
  int* flagCount = (int*)(ws + 66560);
  int* flagList = (int*)(ws + 66576);
  unsigned short* ehT = (unsigned short*)(ws + 99344);

  precompute_kernel<<<132, 256, 0, stream>>>(emb, Csq, ehT, flagCount);
  phase1_kernel<<<256, 512, 0, stream>>>(z, ehT, Csq, emb, A, (float*)d_out,
                                         flagCount, flagList);
  phase2_kernel<<<1024, 256, 0, stream>>>(z, emb, Csq, A, (float*)d_out,
                                          flagCount, flagList);
}

// Round 19
// 101.548 us; speedup vs baseline: 1.0244x; 1.0244x over previous
//
#include <hip/hip_runtime.h>
#include <cfloat>
#include <cstdint>

#define THRESH 1.25e-4f

typedef __attribute__((ext_vector_type(8))) _Float16 half8;        // 8 fp16 (4 VGPR) MFMA A/B frag
typedef __attribute__((ext_vector_type(8))) unsigned short upk8;   // packing vector
typedef __attribute__((ext_vector_type(4))) float facc4;           // MFMA C/D frag
typedef __attribute__((ext_vector_type(4))) float f32x4;           // clang vec for nontemporal st

__device__ __forceinline__ unsigned short f2h(float x) {
  _Float16 h = (_Float16)x;     // RNE
  return __builtin_bit_cast(unsigned short, h);
}

// ws layout (float offsets):
// 0      Csq[1024]
// 1024   A[32768]           (||z||^2, written by phase1)
// 33792  idx[32768] (int)
// 66560  flagCount (int, +16 pad)
// 66576  flagList[32768] (int)
// 99344  ehT[262144] ushort (fp16 codebook, k-major: [kg=32][code=1024][8])

__global__ __launch_bounds__(256) void precompute_kernel(
    const float* __restrict__ emb, float* __restrict__ Csq,
    unsigned short* __restrict__ ehT, int* __restrict__ flagCount) {
  int blk = blockIdx.x, t = threadIdx.x;
  if (blk < 4) {
    int k = blk * 256 + t;
    const float4* e4 = (const float4*)(emb + ((size_t)k << 8));
    double acc = 0.0;
    for (int d4 = 0; d4 < 64; ++d4) {
      float4 e = e4[d4];
      acc += (double)(e.x * e.x) + (double)(e.y * e.y) +
             (double)(e.z * e.z) + (double)(e.w * e.w);
    }
    Csq[k] = (float)acc;
    if (blk == 0 && t == 0) *flagCount = 0;
  } else {
    // k-major fp16 codebook: ehT[(kg*1024 + code)*8 + j] = fp16(emb[code][kg*8+j])
    int linear = (blk - 4) * 256 + t;           // 0..32767
    int code = linear & 1023, kg = linear >> 10;
    const float* ep = emb + ((size_t)code << 8) + (kg << 3);
    float4 e0 = *(const float4*)ep;
    float4 e1 = *(const float4*)(ep + 4);
    upk8 pk;
    pk[0] = f2h(e0.x); pk[1] = f2h(e0.y); pk[2] = f2h(e0.z); pk[3] = f2h(e0.w);
    pk[4] = f2h(e1.x); pk[5] = f2h(e1.y); pk[6] = f2h(e1.z); pk[7] = f2h(e1.w);
    *(upk8*)(ehT + ((size_t)linear << 3)) = pk;
  }
}

// Stage half-slab h (codes h*128 .. h*128+127, all 32 kg-octs) into a 64KB buf.
// LDS layout: [kg=32][cl=128][8 fp16] linear; per wave 8 glds_dwordx4 (vmcnt +8).
// LDS dest = wave-uniform base (HW adds lane*16); global src contiguous 1KB/inst.
__device__ __forceinline__ void stage_half(
    const unsigned short* __restrict__ ehT, char* buf, int h, int t) {
  int w6 = t & 0x1C0;                       // wave<<6
#pragma unroll
  for (int i = 0; i < 8; ++i) {
    int slot = (i << 9) + t;                // 0..4095 (16B units)
    int kg = slot >> 7, cl = slot & 127;
    const unsigned short* g = ehT + (((size_t)(kg << 10) + (h << 7) + cl) << 3);
    char* lp = buf + (((i << 9) + w6) << 4);    // wave-uniform
    __builtin_amdgcn_global_load_lds(
        (const __attribute__((address_space(1))) unsigned int*)g,
        (__attribute__((address_space(3))) unsigned int*)lp, 16, 0, 0);
  }
}

// Phase 1: fp16 MFMA GEMM-argmin, double-buffered half-slab pipeline (T3/T4).
// Block = 128 vectors x 1024 codes, 512 threads (8 waves), grid 256 (1 blk/CU).
// r11 configuration exactly (best verified: 46us, VGPR 112, no spill).
// h-loop NOT unrolled (full unroll -> >128 VGPR -> 80MB scratch, r9/r10).
__global__ __launch_bounds__(512) __attribute__((amdgpu_waves_per_eu(2, 2)))
void phase1_kernel(
    const float* __restrict__ z, const unsigned short* __restrict__ ehT,
    const float* __restrict__ Csq, float* __restrict__ A,
    int* __restrict__ idxbuf, int* __restrict__ flagCount,
    int* __restrict__ flagList) {
  __shared__ char bufA[65536] __attribute__((aligned(16)));
  __shared__ char bufB[65536] __attribute__((aligned(16)));
  __shared__ float Cs[1024];
  __shared__ float mm1[2][4][32], mm2[2][4][32];
  __shared__ int mbi[2][4][32];

  int t = threadIdx.x;
  int n0 = blockIdx.x << 7;                 // 128 vectors per block
  int b = n0 >> 10, wh0 = n0 & 1023;
  int w = t >> 6, l = t & 63;
  int wv = w & 3, wn = w >> 2;
  int lx = l & 15, lg = l >> 4;

  stage_half(ehT, bufA, 0, t);              // halves 0,1 fly during A-phase
  stage_half(ehT, bufB, 1, t);
  ((float2*)Cs)[t] = ((const float2*)Csq)[t];

  // ---- A-fragments from global z (coalesced 64B clusters), norms for free
  half8 afr[2][8];
  double nacc[2] = {0.0, 0.0};
  const float* zb = z + (((size_t)(b * 256)) << 10) + wh0 + wv * 32 + lx;
#pragma unroll
  for (int mi = 0; mi < 2; ++mi) {
#pragma unroll
    for (int kk = 0; kk < 8; ++kk) {
      upk8 pk;
#pragma unroll
      for (int j = 0; j < 8; ++j) {
        int c = kk * 32 + lg * 8 + j;
        float x = zb[((size_t)c << 10) + mi * 16];
        nacc[mi] += (double)(x * x);
        pk[j] = f2h(-2.0f * x);
      }
      afr[mi][kk] = __builtin_bit_cast(half8, pk);
    }
  }
#pragma unroll
  for (int mi = 0; mi < 2; ++mi) {
    double s = nacc[mi];
    s += __shfl_xor(s, 16);
    s += __shfl_xor(s, 32);
    if (wn == 0 && lg == 0) A[n0 + wv * 32 + mi * 16 + lx] = (float)s;
  }
  __syncthreads();   // full drain: halves 0,1 + Cs ready, vmcnt ledger = 0

  float m1[8], m2[8];
  int bi[8];
#pragma unroll
  for (int s8 = 0; s8 < 8; ++s8) { m1[s8] = FLT_MAX; m2[s8] = FLT_MAX; bi[s8] = 0; }

#pragma unroll 1
  for (int h = 0; h < 8; ++h) {
    // ---- compute on resident half h: 32 vec x 64 codes x K=256 per wave
    const char* buf = (h & 1) ? bufB : bufA;
    facc4 acc[2][4];
#pragma unroll
    for (int mi = 0; mi < 2; ++mi)
#pragma unroll
      for (int nj = 0; nj < 4; ++nj) {
        facc4 zf = {0.0f, 0.0f, 0.0f, 0.0f};
        acc[mi][nj] = zf;
      }
#pragma unroll
    for (int kk = 0; kk < 8; ++kk) {
      // addr16 = (kk*4+lg)*128 + wn*64 + nj*16 + lx
      const char* base = buf + (((((kk << 2) + lg) << 7) + (wn << 6) + lx) << 4);
#pragma unroll
      for (int nj = 0; nj < 4; ++nj) {
        half8 bv = *(const half8*)(base + (nj << 8));
        acc[0][nj] = __builtin_amdgcn_mfma_f32_16x16x32_f16(afr[0][kk], bv, acc[0][nj], 0, 0, 0);
        acc[1][nj] = __builtin_amdgcn_mfma_f32_16x16x32_f16(afr[1][kk], bv, acc[1][nj], 0, 0, 0);
      }
    }
    // branchless min-update; C/D frag: col=lane&15 (code), row=lg*4+reg (vector)
    int cbase = (h << 7) + (wn << 6);
#pragma unroll
    for (int nj = 0; nj < 4; ++nj) {
      float csv = Cs[cbase + nj * 16 + lx];
      int code = cbase + nj * 16 + lx;
#pragma unroll
      for (int mi = 0; mi < 2; ++mi)
#pragma unroll
        for (int reg = 0; reg < 4; ++reg) {
          int s8 = mi * 4 + reg;
          float sv = acc[mi][nj][reg] + csv;
          float hi = fmaxf(sv, m1[s8]);
          bool lt = sv < m1[s8];
          m1[s8] = lt ? sv : m1[s8];
          bi[s8] = lt ? code : bi[s8];
          m2[s8] = fminf(m2[s8], hi);
        }
    }
    if (h < 7) {
      asm volatile("s_waitcnt lgkmcnt(0)" ::: "memory");
      __builtin_amdgcn_s_barrier();          // all waves done reading buf[h&1]
      if (h < 6) {
        stage_half(ehT, (h & 1) ? bufB : bufA, h + 2, t);
        asm volatile("s_waitcnt vmcnt(8)" ::: "memory");   // stage(h+1) retired
      } else {
        asm volatile("s_waitcnt vmcnt(0)" ::: "memory");   // last half: full drain
      }
      __builtin_amdgcn_s_barrier();          // buf[(h+1)&1] ready for all waves
    }
  }

  // ---- reduce 16 lanes sharing each vector, then merge the two code-half waves
#pragma unroll
  for (int s8 = 0; s8 < 8; ++s8) {
    float M1 = m1[s8], M2 = m2[s8];
    int BI = bi[s8];
    for (int off = 8; off > 0; off >>= 1) {
      float om1 = __shfl_xor(M1, off, 16);
      float om2 = __shfl_xor(M2, off, 16);
      int obi = __shfl_xor(BI, off, 16);
      float lo = fminf(M2, om2);
      bool take = (om1 < M1) || (om1 == M1 && obi < BI);
      float loser = take ? M1 : om1;
      M2 = fminf(lo, loser);
      if (take) { M1 = om1; BI = obi; }
    }
    if (lx == 0) {
      int row = ((s8 >> 2) << 4) + (lg << 2) + (s8 & 3);
      mm1[wn][wv][row] = M1; mm2[wn][wv][row] = M2; mbi[wn][wv][row] = BI;
    }
  }
  __syncthreads();
  if (wn == 0 && lx == 0) {
#pragma unroll
    for (int s8 = 0; s8 < 8; ++s8) {
      int row = ((s8 >> 2) << 4) + (lg << 2) + (s8 & 3);
      float a1v = mm1[0][wv][row], a2v = mm2[0][wv][row];
      int ab = mbi[0][wv][row];
      float b1v = mm1[1][wv][row], b2v = mm2[1][wv][row];
      int bb = mbi[1][wv][row];
      bool tb = (b1v < a1v) || (b1v == a1v && bb < ab);
      float M1 = tb ? b1v : a1v;
      int BI = tb ? bb : ab;
      float M2 = fminf(fminf(a2v, b2v), tb ? a1v : b1v);
      int n = n0 + wv * 32 + row;
      idxbuf[n] = BI;
      if (M2 - M1 < THRESH) {
        int pos = atomicAdd(flagCount, 1);
        flagList[pos] = n;
      }
    }
  }
}

// Phase 2: fp32 reference-formula emulation for flagged vectors.
// q_k = fp32((A - 2*dot32) + C_k), exact compare, first-index tie-break.
// 4 vectors per block-iteration; each thread owns codes {t, t+256, t+512, t+768}.
__global__ __launch_bounds__(256) void phase2_kernel(
    const float* __restrict__ z, const float* __restrict__ emb,
    const float* __restrict__ Csq, const float* __restrict__ A,
    int* __restrict__ idxbuf, const int* __restrict__ flagCount,
    const int* __restrict__ flagList) {
  __shared__ float zq[4][260];
  __shared__ float Anv[4];
  __shared__ int nn[4];
  __shared__ float sq[4][4];
  __shared__ int sk[4][4];
  int t = threadIdx.x;
  int w = t >> 6, l = t & 63;
  int cnt = *flagCount;
  int nit = (cnt + 3) >> 2;
  for (int it = blockIdx.x; it < nit; it += gridDim.x) {
    __syncthreads();   // protect zq/nn/sq reuse across grid-stride iterations
    int base = it << 2;
    int mcnt = min(4, cnt - base);
    if (t < 4) {
      if (t < mcnt) { int n = flagList[base + t]; nn[t] = n; Anv[t] = A[n]; }
      else nn[t] = -1;
    }
    __syncthreads();
#pragma unroll
    for (int v = 0; v < 4; ++v) {
      int n = nn[v];
      if (n >= 0) {
        int bb = n >> 10, wh = n & 1023;
        zq[v][t] = z[(((size_t)(bb * 256 + t)) << 10) + wh];
      }
    }
    __syncthreads();

    float dot[4][4];
#pragma unroll
    for (int r = 0; r < 4; ++r)
#pragma unroll
      for (int v = 0; v < 4; ++v) dot[r][v] = 0.0f;

    const float4* e0 = (const float4*)(emb + ((size_t)(t + 0) << 8));
    const float4* e1 = (const float4*)(emb + ((size_t)(t + 256) << 8));
    const float4* e2 = (const float4*)(emb + ((size_t)(t + 512) << 8));
    const float4* e3 = (const float4*)(emb + ((size_t)(t + 768) << 8));
#pragma unroll 8
    for (int d4 = 0; d4 < 64; ++d4) {
      float4 ea = e0[d4], eb = e1[d4], ec = e2[d4], ed = e3[d4];
#pragma unroll
      for (int v = 0; v < 4; ++v) {
        float4 zv = *(const float4*)&zq[v][d4 * 4];
        dot[0][v] += zv.x * ea.x + zv.y * ea.y + zv.z * ea.z + zv.w * ea.w;
        dot[1][v] += zv.x * eb.x + zv.y * eb.y + zv.z * eb.z + zv.w * eb.w;
        dot[2][v] += zv.x * ec.x + zv.y * ec.y + zv.z * ec.z + zv.w * ec.w;
        dot[3][v] += zv.x * ed.x + zv.y * ed.y + zv.z * ed.z + zv.w * ed.w;
      }
    }

    float bq[4];
    int bk[4];
#pragma unroll
    for (int v = 0; v < 4; ++v) { bq[v] = FLT_MAX; bk[v] = 0; }
#pragma unroll
    for (int r = 0; r < 4; ++r) {
      int k = t + (r << 8);
      float Ck = Csq[k];
#pragma unroll
      for (int v = 0; v < 4; ++v) {
        float qv = (Anv[v] - 2.0f * dot[r][v]) + Ck;
        if (qv < bq[v]) { bq[v] = qv; bk[v] = k; }   // within-thread k ascending
      }
    }

#pragma unroll
    for (int v = 0; v < 4; ++v) {
      float q = bq[v];
      int kk = bk[v];
      for (int off = 32; off > 0; off >>= 1) {
        float oq = __shfl_xor(q, off);
        int ok = __shfl_xor(kk, off);
        if (oq < q || (oq == q && ok < kk)) { q = oq; kk = ok; }
      }
      if (l == 0) { sq[v][w] = q; sk[v][w] = kk; }
    }
    __syncthreads();
    if (t < mcnt) {
      float q = sq[t][0];
      int kk = sk[t][0];
#pragma unroll
      for (int j = 1; j < 4; ++j) {
        float oq = sq[t][j];
        int ok = sk[t][j];
        if (oq < q || (oq == q && ok < kk)) { q = oq; kk = ok; }
      }
      idxbuf[nn[t]] = kk;
    }
  }
}

// Gather + transpose: out0 = out1 = emb[idx] in [B,C,W,H]; out2 = idx as float.
// float4 + NON-TEMPORAL stores (clang ext_vector type): 64MB streaming writes,
// never re-read -> bypass L2 write-allocate for full write BW.
__global__ __launch_bounds__(256) void gather_kernel(
    const float* __restrict__ emb, const int* __restrict__ idxbuf,
    float* __restrict__ out) {
  __shared__ int sidx[32];
  __shared__ float se[256][36];   // stride 36 words: float4-aligned rows
  int tid = threadIdx.x;
  int blk = blockIdx.x;
  int n0 = blk * 32;
  int b = n0 >> 10, wh0 = n0 & 1023;
  float* out0 = out;
  float* out1 = out + 8388608;
  float* out2 = out + 16777216;
  if (tid < 32) {
    int ix = idxbuf[n0 + tid];
    sidx[tid] = ix;
    out2[n0 + tid] = (float)ix;
  }
  __syncthreads();
  {
    int v = tid >> 3, d8 = tid & 7;
    int row = sidx[v];
    const float4* e4 = (const float4*)(emb + ((size_t)row << 8));
    for (int it = 0; it < 8; ++it) {
      int d4 = it * 8 + d8;
      float4 e = e4[d4];
      se[d4 * 4 + 0][v] = e.x; se[d4 * 4 + 1][v] = e.y;
      se[d4 * 4 + 2][v] = e.z; se[d4 * 4 + 3][v] = e.w;
    }
  }
  __syncthreads();
  {
    int slot = tid & 7, crow = tid >> 3;     // 8 wh-quads x 32 c-rows
#pragma unroll
    for (int it = 0; it < 8; ++it) {
      int c = it * 32 + crow;
      f32x4 val = *(const f32x4*)&se[c][slot * 4];
      size_t o = (((size_t)(b * 256 + c)) << 10) + wh0 + slot * 4;
      __builtin_nontemporal_store(val, (f32x4*)(out0 + o));
      __builtin_nontemporal_store(val, (f32x4*)(out1 + o));
    }
  }
}

extern "C" void kernel_launch(void* const* d_in, const int* in_sizes, int n_in,
                              void* d_out, int out_size, void* d_ws, size_t ws_size,
                              hipStream_t stream) {
  const float* z = (const float*)d_in[0];
  const float* emb = (const float*)d_in[1];
  float* ws = (float*)d_ws;
  float* Csq = ws;
  float* A = ws + 1024;
  int* idxbuf = (int*)(ws + 33792);
  int* flagCount = (int*)(ws + 66560);
  int* flagList = (int*)(ws + 66576);
  unsigned short* ehT = (unsigned short*)(ws + 99344);

  precompute_kernel<<<132, 256, 0, stream>>>(emb, Csq, ehT, flagCount);
  phase1_kernel<<<256, 512, 0, stream>>>(z, ehT, Csq, A, idxbuf, flagCount, flagList);
  phase2_kernel<<<1024, 256, 0, stream>>>(z, emb, Csq, A, idxbuf, flagCount, flagList);
  gather_kernel<<<1024, 256, 0, stream>>>(emb, idxbuf, (float*)d_out);
}